// Round 14
// baseline (208.645 us; speedup 1.0000x reference)
//
#include <hip/hip_runtime.h>
#include <hip/hip_bf16.h>

// Problem: B=8, C=256, H=W=64 -> N=4096, inter=32. fp32 in/out.
#define BB 8
#define CC 256
#define NN 4096
#define II 32
#define LOG2E 1.4426950408889634f

#if __has_builtin(__builtin_amdgcn_exp2f)
#define EXP2F(x) __builtin_amdgcn_exp2f(x)
#else
#define EXP2F(x) exp2f(x)
#endif

#define AS1 __attribute__((address_space(1)))
#define AS3 __attribute__((address_space(3)))

typedef __bf16 bf16_t;
typedef bf16_t bf16x8 __attribute__((ext_vector_type(8)));
typedef float f32x4 __attribute__((ext_vector_type(4)));

// ---------------------------------------------------------------------------
// Weight pre-convert: Wb[320][256] bf16 = [Wq(32); Wk(32); Wv(256)] rows.
// Wq rows pre-scaled by log2(e): attn uses exp2 (v_exp_f32 is native 2^x).
// ---------------------------------------------------------------------------
__global__ __launch_bounds__(256) void wconv(
    const float* __restrict__ Wq, const float* __restrict__ Wk,
    const float* __restrict__ Wv, bf16_t* __restrict__ Wb) {
  int idx = blockIdx.x * 256 + threadIdx.x;  // < 320*256
  int o = idx >> 8, c = idx & 255;
  float w = (o < 32) ? Wq[o * 256 + c] * LOG2E
          : (o < 64) ? Wk[(o - 32) * 256 + c]
                     : Wv[(o - 64) * 256 + c];
  Wb[idx] = (bf16_t)w;
}

// ---------------------------------------------------------------------------
// FUSED x-transpose + q/k/v projection (R8/R11/R12-verified, unchanged).
// V-epilogue writes the PV-fragment-native tiled layout:
//   v2 element (c, n) at index ((c/16)*512 + n/8)*128 + (c%16)*8 + (n%8).
// ---------------------------------------------------------------------------
__global__ __launch_bounds__(256, 2) void qkv_fused(
    const float* __restrict__ x, const bf16_t* __restrict__ Wb,
    const float* __restrict__ bq, const float* __restrict__ bk,
    const float* __restrict__ bv,
    bf16_t* __restrict__ q, bf16_t* __restrict__ k, bf16_t* __restrict__ v) {
  __shared__ bf16_t xs[128][264];  // [n_loc][c], +8 bf16 pad

  const int t  = threadIdx.x;
  const int n0 = blockIdx.x * 128;
  const int og = blockIdx.y;  // o-tile group: tiles [og*10, og*10+10)
  const int b  = blockIdx.z;

  // ---- stage: x[b][c][n0+128) -> xs[n][c] (bf16, transposed) ----
  {
    const float* xb = x + (size_t)b * CC * NN + n0;
    const int cq  = t >> 2;         // c-quad 0..63
    const int nq4 = (t & 3) * 4;    // n offset within 16-group
#pragma unroll
    for (int p = 0; p < 8; ++p) {
      const int nb = p * 16 + nq4;
      float4 r0 = *(const float4*)&xb[(size_t)(cq * 4 + 0) * NN + nb];
      float4 r1 = *(const float4*)&xb[(size_t)(cq * 4 + 1) * NN + nb];
      float4 r2 = *(const float4*)&xb[(size_t)(cq * 4 + 2) * NN + nb];
      float4 r3 = *(const float4*)&xb[(size_t)(cq * 4 + 3) * NN + nb];
      float c0[4] = {r0.x, r0.y, r0.z, r0.w};
      float c1[4] = {r1.x, r1.y, r1.z, r1.w};
      float c2[4] = {r2.x, r2.y, r2.z, r2.w};
      float c3[4] = {r3.x, r3.y, r3.z, r3.w};
#pragma unroll
      for (int jj = 0; jj < 4; ++jj) {
        union { bf16_t h[4]; uint2 u; } pk;
        pk.h[0] = (bf16_t)c0[jj]; pk.h[1] = (bf16_t)c1[jj];
        pk.h[2] = (bf16_t)c2[jj]; pk.h[3] = (bf16_t)c3[jj];
        *(uint2*)&xs[nb + jj][cq * 4] = pk.u;
      }
    }
  }
  __syncthreads();

  // ---- GEMM: 4 waves, wave w = n-sub [w*32, w*32+32) ----
  const int w  = t >> 6;
  const int l  = t & 63;
  const int lo = l & 15;
  const int q4 = l >> 4;
  const int nbase = n0 + w * 32;  // global n for epilogue

  f32x4 acc[10][2];
#pragma unroll
  for (int ot = 0; ot < 10; ++ot)
#pragma unroll
    for (int ms = 0; ms < 2; ++ms) acc[ot][ms] = (f32x4){0.f, 0.f, 0.f, 0.f};

#pragma unroll 2
  for (int ks = 0; ks < 8; ++ks) {
    const int c0 = ks * 32 + q4 * 8;
    bf16x8 af[2];
#pragma unroll
    for (int ms = 0; ms < 2; ++ms)
      af[ms] = *(const bf16x8*)&xs[w * 32 + ms * 16 + lo][c0];
    bf16x8 bw[10];
#pragma unroll
    for (int ot = 0; ot < 10; ++ot)
      bw[ot] = *(const bf16x8*)&Wb[((og * 10 + ot) * 16 + lo) * 256 + c0];
#pragma unroll
    for (int ms = 0; ms < 2; ++ms)
#pragma unroll
      for (int ot = 0; ot < 10; ++ot)
        acc[ot][ms] = __builtin_amdgcn_mfma_f32_16x16x32_bf16(
            af[ms], bw[ot], acc[ot][ms], 0, 0, 0);
  }

  // Epilogue: q,k -> [b][n][32] bf16; v -> v2 tiled layout (see header).
#pragma unroll
  for (int ot = 0; ot < 10; ++ot) {
    const int gt = og * 10 + ot;  // global o-tile 0..19
    if (gt < 4) {
      const bool isq = gt < 2;
      const int i = (gt & 1) * 16 + lo;
      const float bias = isq ? bq[i] * LOG2E : bk[i];
      bf16_t* dst = (isq ? q : k) + (size_t)b * NN * II;
#pragma unroll
      for (int ms = 0; ms < 2; ++ms) {
#pragma unroll
        for (int r = 0; r < 4; ++r) {
          int n = nbase + ms * 16 + q4 * 4 + r;
          dst[(size_t)n * II + i] = (bf16_t)(acc[ot][ms][r] + bias);
        }
      }
    } else {
      const int ctg = gt - 4;  // c-tile 0..15; this lane's c = ctg*16 + lo
      const float bias = bv[ctg * 16 + lo];
      bf16_t* dst = v + (size_t)b * CC * NN;
#pragma unroll
      for (int ms = 0; ms < 2; ++ms) {
        union { bf16_t h[4]; uint2 u; } pk;
#pragma unroll
        for (int r = 0; r < 4; ++r) pk.h[r] = (bf16_t)(acc[ot][ms][r] + bias);
        // n = nbase + ms*16 + q4*4 + r  ->  g = n>>3, nl = n&7
        const size_t idx =
            (((size_t)ctg * 512 + (nbase >> 3) + ms * 2 + (q4 >> 1)) * 16 + lo) * 8
            + (q4 & 1) * 4;
        *(uint2*)&dst[idx] = pk.u;
      }
    }
  }
}

// ---------------------------------------------------------------------------
// MFMA attention: R12 geometry (256-thr, m-64, grid 512, n-64 iters, 8-chunk
// P swizzle = the 2.1M-conflict config) with V staged via ASYNC
// global_load_lds instead of register loads.
// WHY: R12/R13 plateau at 85-89us, MfmaUtil ~39%, VMEM 22 B/cyc/CU vs the
// ~29 ceiling (R9) -- residual is exposed V-load latency because the
// allocator keeps sinking register V-loads (R12 VGPR=104: one buffer kept,
// one discarded). global_load_lds takes V out of the VGPR budget: loads are
// issued async (no dest register, can't be sunk) a full phase ahead.
// KEY STRUCTURAL FACT: wave w reads ONLY its own c-slice Vld[w] -> staging
// is wave-private; the existing per-iter vmcnt(0)+barrier (required for P
// anyway) already guarantees arrival; buffer reuse needs no extra barrier
// (wave w's own lgkm-complete ds_reads precede its next-tile stage issue,
// pinned by sched_barrier).
// v2 layout matches gload_lds semantics exactly (gotcha #21): LDS dest =
// wave-uniform base + lane*16B (linear), global src per-lane; element
// mapping is bit-identical to the verified register version.
// Phase-2 V reads: contiguous ds_read_b128 (2-way aliasing = free).
// ---------------------------------------------------------------------------
__global__ __launch_bounds__(256, 2) void attn_mfma(
    const bf16_t* __restrict__ q, const bf16_t* __restrict__ k,
    const bf16_t* __restrict__ v, const float* __restrict__ x,
    const float* __restrict__ gamma, float* __restrict__ out) {
  __shared__ bf16_t Pld[2][64 * 64];   // 16 KB double-buffered P
  __shared__ bf16_t Vld[4][8][512];    // 32 KB: [wave][frag][1KB tile]
  __shared__ float lred[16][64];
  __shared__ float lfin[64];

  const int t  = threadIdx.x;
  const int w  = t >> 6;   // wave id = c-split
  const int l  = t & 63;
  const int lo = l & 15;
  const int q4 = l >> 4;
  const int bid = blockIdx.x;
  const int b   = bid & 7;        // XCD-pinned batch (256-thr verified)
  const int m0  = (bid >> 3) * 64;

  const bf16_t* qb = q + (size_t)b * NN * II;
  const bf16_t* kb = k + (size_t)b * NN * II;
  const bf16_t* vb = v + (size_t)b * CC * NN;  // v2 tiled layout

  // Q B-frags, loop-invariant, in registers
  bf16x8 qf[4];
#pragma unroll
  for (int mt = 0; mt < 4; ++mt)
    qf[mt] = *(const bf16x8*)(qb + (size_t)(m0 + mt * 16 + lo) * II + q4 * 8);

  f32x4 acc[4][4];  // [ct][mt]
#pragma unroll
  for (int ct = 0; ct < 4; ++ct)
#pragma unroll
    for (int mt = 0; mt < 4; ++mt) acc[ct][mt] = (f32x4){0.f, 0.f, 0.f, 0.f};
  float lp[4] = {0.f, 0.f, 0.f, 0.f};

  const f32x4 zero = (f32x4){0.f, 0.f, 0.f, 0.f};

  // Async stage of tile NT's V frags for this wave into Vld[w] (8 x 1KB).
  // LDS dest: uniform base, lane i auto-writes +i*16B; global src per-lane.
#define STAGE_V(NT)                                                           \
  {                                                                           \
    _Pragma("unroll")                                                         \
    for (int kc = 0; kc < 2; ++kc)                                            \
      _Pragma("unroll")                                                       \
      for (int ct = 0; ct < 4; ++ct) {                                        \
        const bf16_t* gp = vb +                                               \
            ((size_t)(w * 4 + ct) * 512 + ((NT) >> 3) + kc * 4) * 128 + l * 8;\
        __builtin_amdgcn_global_load_lds((const AS1 void*)gp,                 \
            (AS3 void*)&Vld[w][kc * 4 + ct][0], 16, 0, 0);                    \
      }                                                                       \
  }

  // ---- prime: stage V tile 0, load K frag for tile 0 ----
  STAGE_V(0)
  bf16x8 kf = *(const bf16x8*)(kb + (size_t)(w * 16 + lo) * II + q4 * 8);

  for (int n1 = 0, it = 0; n1 < NN; n1 += 64, ++it) {
    // ---- K frag for NEXT tile (register; full-iter slack) ----
    const int n_next = (n1 + 64) & (NN - 1);  // wraps on last iter (discarded)
    bf16x8 kf_next = *(const bf16x8*)(kb + (size_t)(n_next + w * 16 + lo) * II + q4 * 8);

    // ---- Phase 1: scores for n-sub w (V[n1] staging in flight) ----
    bf16_t* Pb = Pld[it & 1];
#pragma unroll
    for (int mt = 0; mt < 4; ++mt) {
      f32x4 s = __builtin_amdgcn_mfma_f32_16x16x32_bf16(kf, qf[mt], zero, 0, 0, 0);
      float e0 = EXP2F(s[0]), e1 = EXP2F(s[1]);
      float e2 = EXP2F(s[2]), e3 = EXP2F(s[3]);
      lp[mt] += (e0 + e1) + (e2 + e3);
      union { bf16_t h[4]; uint2 u2; } ph;
      ph.h[0] = (bf16_t)e0; ph.h[1] = (bf16_t)e1;
      ph.h[2] = (bf16_t)e2; ph.h[3] = (bf16_t)e3;
      // P[m][n_local], n_local = w*16 + q4*4 + r. 16B chunk c8 at row m
      // lives at phys chunk c8 ^ (m&7). Write = 8B half-chunk.
      int m_loc = mt * 16 + lo;
      int c8    = w * 2 + (q4 >> 1);
      int elem  = m_loc * 64 + ((c8 ^ (m_loc & 7)) * 8) + (q4 & 1) * 4;
      *(uint2*)&Pb[elem] = ph.u2;
    }

    // ---- full drain + barrier: P writes ordered for all waves AND this
    //      wave's V staging (vmcnt) completed into Vld[w] ----
    asm volatile("s_waitcnt vmcnt(0) lgkmcnt(0)" ::: "memory");
    __builtin_amdgcn_s_barrier();
    __builtin_amdgcn_sched_barrier(0);  // don't hoist ds_reads above barrier

    // ---- Phase 2: PV (V from LDS, contiguous b128; P swizzled) ----
#pragma unroll
    for (int kc = 0; kc < 2; ++kc) {
      bf16x8 pf[4];
#pragma unroll
      for (int mt = 0; mt < 4; ++mt) {
        int m_loc = mt * 16 + lo;
        int c8    = kc * 4 + q4;
        pf[mt] = *(const bf16x8*)&Pb[m_loc * 64 + ((c8 ^ (m_loc & 7)) * 8)];
      }
      __builtin_amdgcn_s_setprio(1);
#pragma unroll
      for (int ct = 0; ct < 4; ++ct) {
        const bf16x8 vfc = *(const bf16x8*)&Vld[w][kc * 4 + ct][l * 8];
#pragma unroll
        for (int mt = 0; mt < 4; ++mt)
          acc[ct][mt] = __builtin_amdgcn_mfma_f32_16x16x32_bf16(
              vfc, pf[mt], acc[ct][mt], 0, 0, 0);
      }
      __builtin_amdgcn_s_setprio(0);
    }

    // ---- issue NEXT tile's V staging (wave-private buffer: only this
    //      wave's reads guard reuse; they are lgkm-complete by the MFMAs).
    //      sched_barrier pins the issue below the ds_reads. ----
    __builtin_amdgcn_sched_barrier(0);
    asm volatile("s_waitcnt lgkmcnt(0)" ::: "memory");
    STAGE_V(n_next)
    kf = kf_next;
  }

  // ---- softmax denominator reduction ----
#pragma unroll
  for (int mt = 0; mt < 4; ++mt) lred[w * 4 + q4][mt * 16 + lo] = lp[mt];
  __syncthreads();
  if (t < 64) {
    float s = 0.f;
#pragma unroll
    for (int j = 0; j < 16; ++j) s += lred[j][t];
    lfin[t] = s;
  }
  __syncthreads();

  const float g = gamma[0];
  float linv[4];
#pragma unroll
  for (int mt = 0; mt < 4; ++mt) linv[mt] = 1.0f / lfin[mt * 16 + lo];

  // ---- epilogue: out = gamma * O/l + x ----
  const int cbase = w * 64;
#pragma unroll
  for (int ct = 0; ct < 4; ++ct) {
#pragma unroll
    for (int r = 0; r < 4; ++r) {
      int c = cbase + ct * 16 + q4 * 4 + r;
      const float* xrow = x + ((size_t)b * CC + c) * NN + m0;
      float* orow       = out + ((size_t)b * CC + c) * NN + m0;
#pragma unroll
      for (int mt = 0; mt < 4; ++mt) {
        int m = mt * 16 + lo;
        orow[m] = g * acc[ct][mt][r] * linv[mt] + xrow[m];
      }
    }
  }
}

// ---------------------------------------------------------------------------
extern "C" void kernel_launch(void* const* d_in, const int* in_sizes, int n_in,
                              void* d_out, int out_size, void* d_ws, size_t ws_size,
                              hipStream_t stream) {
  const float* x     = (const float*)d_in[0];
  const float* Wq    = (const float*)d_in[1];
  const float* bq    = (const float*)d_in[2];
  const float* Wk    = (const float*)d_in[3];
  const float* bk    = (const float*)d_in[4];
  const float* Wv    = (const float*)d_in[5];
  const float* bv    = (const float*)d_in[6];
  const float* gamma = (const float*)d_in[7];
  float* out = (float*)d_out;

  // Workspace (bf16): q 2MB, k 2MB, v 16MB, Wb 160KB (~20.2MB)
  bf16_t* ws = (bf16_t*)d_ws;
  bf16_t* q  = ws;
  bf16_t* k  = q + (size_t)BB * NN * II;
  bf16_t* v  = k + (size_t)BB * NN * II;
  bf16_t* Wb = v + (size_t)BB * CC * NN;

  wconv<<<dim3(320), 256, 0, stream>>>(Wq, Wk, Wv, Wb);

  dim3 gp(NN / 128, 2, BB);
  qkv_fused<<<gp, 256, 0, stream>>>(x, Wb, bq, bk, bv, q, k, v);

  attn_mfma<<<dim3(512), 256, 0, stream>>>(q, k, v, x, gamma, out);
}

// Round 15
// 192.391 us; speedup vs baseline: 1.0845x; 1.0845x over previous
//
#include <hip/hip_runtime.h>
#include <hip/hip_bf16.h>

// Problem: B=8, C=256, H=W=64 -> N=4096, inter=32. fp32 in/out.
#define BB 8
#define CC 256
#define NN 4096
#define II 32
#define LOG2E 1.4426950408889634f

#if __has_builtin(__builtin_amdgcn_exp2f)
#define EXP2F(x) __builtin_amdgcn_exp2f(x)
#else
#define EXP2F(x) exp2f(x)
#endif

typedef __bf16 bf16_t;
typedef bf16_t bf16x8 __attribute__((ext_vector_type(8)));
typedef float f32x4 __attribute__((ext_vector_type(4)));

// ---------------------------------------------------------------------------
// Weight pre-convert: Wb[320][256] bf16 = [Wq(32); Wk(32); Wv(256)] rows.
// Wq rows pre-scaled by log2(e): attn uses exp2 (v_exp_f32 is native 2^x).
// ---------------------------------------------------------------------------
__global__ __launch_bounds__(256) void wconv(
    const float* __restrict__ Wq, const float* __restrict__ Wk,
    const float* __restrict__ Wv, bf16_t* __restrict__ Wb) {
  int idx = blockIdx.x * 256 + threadIdx.x;  // < 320*256
  int o = idx >> 8, c = idx & 255;
  float w = (o < 32) ? Wq[o * 256 + c] * LOG2E
          : (o < 64) ? Wk[(o - 32) * 256 + c]
                     : Wv[(o - 64) * 256 + c];
  Wb[idx] = (bf16_t)w;
}

// ---------------------------------------------------------------------------
// FUSED x-transpose + q/k/v projection (R8/R11/R12-verified, unchanged).
// V-epilogue writes the PV-fragment-native tiled layout:
//   v2 element (c, n) at index ((c/16)*512 + n/8)*128 + (c%16)*8 + (n%8).
// ---------------------------------------------------------------------------
__global__ __launch_bounds__(256, 2) void qkv_fused(
    const float* __restrict__ x, const bf16_t* __restrict__ Wb,
    const float* __restrict__ bq, const float* __restrict__ bk,
    const float* __restrict__ bv,
    bf16_t* __restrict__ q, bf16_t* __restrict__ k, bf16_t* __restrict__ v) {
  __shared__ bf16_t xs[128][264];  // [n_loc][c], +8 bf16 pad

  const int t  = threadIdx.x;
  const int n0 = blockIdx.x * 128;
  const int og = blockIdx.y;  // o-tile group: tiles [og*10, og*10+10)
  const int b  = blockIdx.z;

  // ---- stage: x[b][c][n0+128) -> xs[n][c] (bf16, transposed) ----
  {
    const float* xb = x + (size_t)b * CC * NN + n0;
    const int cq  = t >> 2;         // c-quad 0..63
    const int nq4 = (t & 3) * 4;    // n offset within 16-group
#pragma unroll
    for (int p = 0; p < 8; ++p) {
      const int nb = p * 16 + nq4;
      float4 r0 = *(const float4*)&xb[(size_t)(cq * 4 + 0) * NN + nb];
      float4 r1 = *(const float4*)&xb[(size_t)(cq * 4 + 1) * NN + nb];
      float4 r2 = *(const float4*)&xb[(size_t)(cq * 4 + 2) * NN + nb];
      float4 r3 = *(const float4*)&xb[(size_t)(cq * 4 + 3) * NN + nb];
      float c0[4] = {r0.x, r0.y, r0.z, r0.w};
      float c1[4] = {r1.x, r1.y, r1.z, r1.w};
      float c2[4] = {r2.x, r2.y, r2.z, r2.w};
      float c3[4] = {r3.x, r3.y, r3.z, r3.w};
#pragma unroll
      for (int jj = 0; jj < 4; ++jj) {
        union { bf16_t h[4]; uint2 u; } pk;
        pk.h[0] = (bf16_t)c0[jj]; pk.h[1] = (bf16_t)c1[jj];
        pk.h[2] = (bf16_t)c2[jj]; pk.h[3] = (bf16_t)c3[jj];
        *(uint2*)&xs[nb + jj][cq * 4] = pk.u;
      }
    }
  }
  __syncthreads();

  // ---- GEMM: 4 waves, wave w = n-sub [w*32, w*32+32) ----
  const int w  = t >> 6;
  const int l  = t & 63;
  const int lo = l & 15;
  const int q4 = l >> 4;
  const int nbase = n0 + w * 32;  // global n for epilogue

  f32x4 acc[10][2];
#pragma unroll
  for (int ot = 0; ot < 10; ++ot)
#pragma unroll
    for (int ms = 0; ms < 2; ++ms) acc[ot][ms] = (f32x4){0.f, 0.f, 0.f, 0.f};

#pragma unroll 2
  for (int ks = 0; ks < 8; ++ks) {
    const int c0 = ks * 32 + q4 * 8;
    bf16x8 af[2];
#pragma unroll
    for (int ms = 0; ms < 2; ++ms)
      af[ms] = *(const bf16x8*)&xs[w * 32 + ms * 16 + lo][c0];
    bf16x8 bw[10];
#pragma unroll
    for (int ot = 0; ot < 10; ++ot)
      bw[ot] = *(const bf16x8*)&Wb[((og * 10 + ot) * 16 + lo) * 256 + c0];
#pragma unroll
    for (int ms = 0; ms < 2; ++ms)
#pragma unroll
      for (int ot = 0; ot < 10; ++ot)
        acc[ot][ms] = __builtin_amdgcn_mfma_f32_16x16x32_bf16(
            af[ms], bw[ot], acc[ot][ms], 0, 0, 0);
  }

  // Epilogue: q,k -> [b][n][32] bf16; v -> v2 tiled layout (see header).
#pragma unroll
  for (int ot = 0; ot < 10; ++ot) {
    const int gt = og * 10 + ot;  // global o-tile 0..19
    if (gt < 4) {
      const bool isq = gt < 2;
      const int i = (gt & 1) * 16 + lo;
      const float bias = isq ? bq[i] * LOG2E : bk[i];
      bf16_t* dst = (isq ? q : k) + (size_t)b * NN * II;
#pragma unroll
      for (int ms = 0; ms < 2; ++ms) {
#pragma unroll
        for (int r = 0; r < 4; ++r) {
          int n = nbase + ms * 16 + q4 * 4 + r;
          dst[(size_t)n * II + i] = (bf16_t)(acc[ot][ms][r] + bias);
        }
      }
    } else {
      const int ctg = gt - 4;  // c-tile 0..15; this lane's c = ctg*16 + lo
      const float bias = bv[ctg * 16 + lo];
      bf16_t* dst = v + (size_t)b * CC * NN;
#pragma unroll
      for (int ms = 0; ms < 2; ++ms) {
        union { bf16_t h[4]; uint2 u; } pk;
#pragma unroll
        for (int r = 0; r < 4; ++r) pk.h[r] = (bf16_t)(acc[ot][ms][r] + bias);
        // n = nbase + ms*16 + q4*4 + r  ->  g = n>>3, nl = n&7
        const size_t idx =
            (((size_t)ctg * 512 + (nbase >> 3) + ms * 2 + (q4 >> 1)) * 16 + lo) * 8
            + (q4 & 1) * 4;
        *(uint2*)&dst[idx] = pk.u;
      }
    }
  }
}

// ---------------------------------------------------------------------------
// MFMA attention: R12 configuration, reverted verbatim (best verified:
// attn 86.5us / total 192.5us).
// 256-thr, m-64, grid 512 (verified invariants: 1GB V-traffic, bid&7
// batch->XCD pinning FETCH~28MB, v2 coalesced V loads, 8-chunk P swizzle
// 2.1M conflicts) + one-tile-ahead register double-buffer of V/K frags
// (compiler adopts ~1 buffer: VGPR 104; best achievable -- R13 barrier
// halving was within noise, R14 async-LDS staging regressed to 104us).
// At 86.5us attn = 894 TF = 36% dense peak, matching the documented
// plain-HIP structure ceiling (~900 TF) for this class of schedule.
// ---------------------------------------------------------------------------
#define PREFETCH(NTILE, KF, VF)                                               \
  {                                                                           \
    const int nn_ = (NTILE);                                                  \
    KF = *(const bf16x8*)(kb + (size_t)(nn_ + w * 16 + lo) * II + q4 * 8);    \
    _Pragma("unroll")                                                         \
    for (int kc = 0; kc < 2; ++kc)                                            \
      _Pragma("unroll")                                                       \
      for (int ct = 0; ct < 4; ++ct)                                          \
        VF[kc * 4 + ct] = *(const bf16x8*)(vb +                               \
            ((size_t)(w * 4 + ct) * 512 + (nn_ >> 3) + kc * 4) * 128 + l * 8);\
  }

#define ATTN_STEP(KF, VF, PBUF)                                               \
  {                                                                           \
    bf16_t* Pb = (PBUF);                                                      \
    _Pragma("unroll")                                                         \
    for (int mt = 0; mt < 4; ++mt) {                                          \
      f32x4 s = __builtin_amdgcn_mfma_f32_16x16x32_bf16(KF, qf[mt], zero, 0, 0, 0); \
      float e0 = EXP2F(s[0]), e1 = EXP2F(s[1]);                               \
      float e2 = EXP2F(s[2]), e3 = EXP2F(s[3]);                               \
      lp[mt] += (e0 + e1) + (e2 + e3);                                        \
      union { bf16_t h[4]; uint2 u2; } ph;                                    \
      ph.h[0] = (bf16_t)e0; ph.h[1] = (bf16_t)e1;                             \
      ph.h[2] = (bf16_t)e2; ph.h[3] = (bf16_t)e3;                             \
      int m_loc = mt * 16 + lo;                                               \
      int c8    = w * 2 + (q4 >> 1);                                          \
      int elem  = m_loc * 64 + ((c8 ^ (m_loc & 7)) * 8) + (q4 & 1) * 4;       \
      *(uint2*)&Pb[elem] = ph.u2;                                             \
    }                                                                         \
    asm volatile("s_waitcnt lgkmcnt(0)" ::: "memory");                        \
    __builtin_amdgcn_s_barrier();                                             \
    __builtin_amdgcn_sched_barrier(0);                                        \
    _Pragma("unroll")                                                         \
    for (int kc = 0; kc < 2; ++kc) {                                          \
      bf16x8 pf[4];                                                           \
      _Pragma("unroll")                                                       \
      for (int mt = 0; mt < 4; ++mt) {                                        \
        int m_loc = mt * 16 + lo;                                             \
        int c8    = kc * 4 + q4;                                              \
        pf[mt] = *(const bf16x8*)&Pb[m_loc * 64 + ((c8 ^ (m_loc & 7)) * 8)];  \
      }                                                                       \
      __builtin_amdgcn_s_setprio(1);                                          \
      _Pragma("unroll")                                                       \
      for (int ct = 0; ct < 4; ++ct)                                          \
        _Pragma("unroll")                                                     \
        for (int mt = 0; mt < 4; ++mt)                                        \
          acc[ct][mt] = __builtin_amdgcn_mfma_f32_16x16x32_bf16(              \
              VF[kc * 4 + ct], pf[mt], acc[ct][mt], 0, 0, 0);                 \
      __builtin_amdgcn_s_setprio(0);                                          \
    }                                                                         \
  }

__global__ __launch_bounds__(256, 2) void attn_mfma(
    const bf16_t* __restrict__ q, const bf16_t* __restrict__ k,
    const bf16_t* __restrict__ v, const float* __restrict__ x,
    const float* __restrict__ gamma, float* __restrict__ out) {
  __shared__ bf16_t Pld[2][64 * 64];  // 16 KB double-buffered P
  __shared__ float lred[16][64];
  __shared__ float lfin[64];

  const int t  = threadIdx.x;
  const int w  = t >> 6;   // wave id = c-split
  const int l  = t & 63;
  const int lo = l & 15;
  const int q4 = l >> 4;
  const int bid = blockIdx.x;
  const int b   = bid & 7;        // XCD-pinned batch (256-thr verified)
  const int m0  = (bid >> 3) * 64;

  const bf16_t* qb = q + (size_t)b * NN * II;
  const bf16_t* kb = k + (size_t)b * NN * II;
  const bf16_t* vb = v + (size_t)b * CC * NN;  // v2 tiled layout

  // Q B-frags, loop-invariant, in registers
  bf16x8 qf[4];
#pragma unroll
  for (int mt = 0; mt < 4; ++mt)
    qf[mt] = *(const bf16x8*)(qb + (size_t)(m0 + mt * 16 + lo) * II + q4 * 8);

  f32x4 acc[4][4];  // [ct][mt]
#pragma unroll
  for (int ct = 0; ct < 4; ++ct)
#pragma unroll
    for (int mt = 0; mt < 4; ++mt) acc[ct][mt] = (f32x4){0.f, 0.f, 0.f, 0.f};
  float lp[4] = {0.f, 0.f, 0.f, 0.f};

  const f32x4 zero = (f32x4){0.f, 0.f, 0.f, 0.f};

  // ---- prime buffer A with tile 0 ----
  bf16x8 kfA, kfB;
  bf16x8 vfA[8], vfB[8];
  PREFETCH(0, kfA, vfA)

  for (int n1 = 0; n1 < NN; n1 += 128) {
    // sub-iter A: prefetch tile n1+64 -> B; compute tile n1 from A -> Pld[0]
    PREFETCH(n1 + 64, kfB, vfB)
    ATTN_STEP(kfA, vfA, Pld[0])
    // sub-iter B: prefetch tile n1+128 -> A; compute tile n1+64 from B -> Pld[1]
    PREFETCH((n1 + 128) & (NN - 1), kfA, vfA)   // wraps on last iter (discarded)
    ATTN_STEP(kfB, vfB, Pld[1])
  }

  // ---- softmax denominator reduction ----
#pragma unroll
  for (int mt = 0; mt < 4; ++mt) lred[w * 4 + q4][mt * 16 + lo] = lp[mt];
  __syncthreads();
  if (t < 64) {
    float s = 0.f;
#pragma unroll
    for (int j = 0; j < 16; ++j) s += lred[j][t];
    lfin[t] = s;
  }
  __syncthreads();

  const float g = gamma[0];
  float linv[4];
#pragma unroll
  for (int mt = 0; mt < 4; ++mt) linv[mt] = 1.0f / lfin[mt * 16 + lo];

  // ---- epilogue: out = gamma * O/l + x ----
  const int cbase = w * 64;
#pragma unroll
  for (int ct = 0; ct < 4; ++ct) {
#pragma unroll
    for (int r = 0; r < 4; ++r) {
      int c = cbase + ct * 16 + q4 * 4 + r;
      const float* xrow = x + ((size_t)b * CC + c) * NN + m0;
      float* orow       = out + ((size_t)b * CC + c) * NN + m0;
#pragma unroll
      for (int mt = 0; mt < 4; ++mt) {
        int m = mt * 16 + lo;
        orow[m] = g * acc[ct][mt][r] * linv[mt] + xrow[m];
      }
    }
  }
}

// ---------------------------------------------------------------------------
extern "C" void kernel_launch(void* const* d_in, const int* in_sizes, int n_in,
                              void* d_out, int out_size, void* d_ws, size_t ws_size,
                              hipStream_t stream) {
  const float* x     = (const float*)d_in[0];
  const float* Wq    = (const float*)d_in[1];
  const float* bq    = (const float*)d_in[2];
  const float* Wk    = (const float*)d_in[3];
  const float* bk    = (const float*)d_in[4];
  const float* Wv    = (const float*)d_in[5];
  const float* bv    = (const float*)d_in[6];
  const float* gamma = (const float*)d_in[7];
  float* out = (float*)d_out;

  // Workspace (bf16): q 2MB, k 2MB, v 16MB, Wb 160KB (~20.2MB)
  bf16_t* ws = (bf16_t*)d_ws;
  bf16_t* q  = ws;
  bf16_t* k  = q + (size_t)BB * NN * II;
  bf16_t* v  = k + (size_t)BB * NN * II;
  bf16_t* Wb = v + (size_t)BB * CC * NN;

  wconv<<<dim3(320), 256, 0, stream>>>(Wq, Wk, Wv, Wb);

  dim3 gp(NN / 128, 2, BB);
  qkv_fused<<<gp, 256, 0, stream>>>(x, Wb, bq, bk, bv, q, k, v);

  attn_mfma<<<dim3(512), 256, 0, stream>>>(q, k, v, x, gamma, out);
}